// Round 12
// baseline (221.880 us; speedup 1.0000x reference)
//
#include <hip/hip_runtime.h>
#include <hip/hip_bf16.h>

#define L_SEQ 200
#define DIM 128
#define NROWS (256*200)

#define W4 49152                 // weight float4 count
#define U4 (50001*DIM/4)         // user-table float4 count (1600032)
#define WBLK 192
#define UBLK ((U4 + 255)/256)    // 6251
#define EBLK (NROWS/4)           // 12800

typedef __attribute__((ext_vector_type(8))) short bf16x8;
typedef __attribute__((ext_vector_type(4))) float f32x4;

__device__ __forceinline__ float wave_sum(float v){
  #pragma unroll
  for (int o = 32; o; o >>= 1) v += __shfl_xor(v, o);
  return v;
}
__device__ __forceinline__ short f2bf(float f){
  union { float f; unsigned u; } x; x.f = f;
  unsigned r = x.u + 0x7fffu + ((x.u >> 16) & 1u);
  return (short)(r >> 16);
}
__device__ __forceinline__ float bf2f(unsigned short u){
  union { unsigned u; float f; } x; x.u = ((unsigned)u) << 16;
  return x.f;
}

// One launch: weight cvt (blocks 0..191), user-table cvt (next 6251),
// embed+LN (last 12800). All sections independent.
__global__ __launch_bounds__(256) void prep_kernel(
    const float* __restrict__ Wqkv, const float* __restrict__ Wo,
    const float* __restrict__ W1, const float* __restrict__ W2,
    short* __restrict__ wdst,
    const float* __restrict__ user, short* __restrict__ user_b,
    const int* __restrict__ lsq, const float* __restrict__ item,
    const float* __restrict__ pos,
    const float* __restrict__ s, const float* __restrict__ b,
    short* __restrict__ seqs_b, short* __restrict__ lnq_b, short* __restrict__ qn_b){
  int bid = blockIdx.x;
  if (bid < WBLK) {
    int i = bid*256 + threadIdx.x;
    if (i < W4) {
      const float* src; int off;
      if (i < 24576)      { src = Wqkv; off = i; }
      else if (i < 32768) { src = Wo;   off = i - 24576; }
      else if (i < 40960) { src = W1;   off = i - 32768; }
      else                { src = W2;   off = i - 40960; }
      float4 v = ((const float4*)src)[off];
      short4 sv; sv.x = f2bf(v.x); sv.y = f2bf(v.y); sv.z = f2bf(v.z); sv.w = f2bf(v.w);
      ((short4*)wdst)[i] = sv;
    }
    return;
  }
  bid -= WBLK;
  if (bid < UBLK) {
    int i = bid*256 + threadIdx.x;
    if (i < U4) {
      float4 v = ((const float4*)user)[i];
      short4 sv; sv.x = f2bf(v.x); sv.y = f2bf(v.y); sv.z = f2bf(v.z); sv.w = f2bf(v.w);
      ((short4*)user_b)[i] = sv;
    }
    return;
  }
  bid -= UBLK;
  // embed + LN: 4 waves, one row each
  int wave = threadIdx.x >> 6, lane = threadIdx.x & 63;
  size_t r = (size_t)bid*4 + wave;
  int it = lsq[r];
  float2 iv = ((const float2*)(item + (size_t)it*DIM))[lane];
  float2 p = ((const float2*)(pos + (r % L_SEQ)*DIM))[lane];
  short2 qv; qv.x = f2bf(iv.x); qv.y = f2bf(iv.y);
  ((short2*)(qn_b + r*DIM))[lane] = qv;
  float vx = 0.f, vy = 0.f;
  if (it) {
    vx = iv.x * 11.313708498984761f + p.x;
    vy = iv.y * 11.313708498984761f + p.y;
  }
  short2 sv; sv.x = f2bf(vx); sv.y = f2bf(vy);
  ((short2*)(seqs_b + r*DIM))[lane] = sv;
  float mu = wave_sum(vx + vy) * (1.f/DIM);
  float dx = vx - mu, dy = vy - mu;
  float var = wave_sum(dx*dx + dy*dy) * (1.f/DIM);
  float inv = 1.f / sqrtf(var + 1e-8f);
  float2 sc = ((const float2*)s)[lane];
  float2 bc = ((const float2*)b)[lane];
  short2 ov; ov.x = f2bf(dx*inv*sc.x + bc.x); ov.y = f2bf(dy*inv*sc.y + bc.y);
  ((short2*)(lnq_b + r*DIM))[lane] = ov;
}

#define MLP_MFMA(accv) do { \
  _Pragma("unroll") \
  for (int kc = 0; kc < 4; ++kc) { \
    bf16x8 af[4], bfr[2]; \
    _Pragma("unroll") \
    for (int mf = 0; mf < 4; ++mf) { \
      int rr = mbase + mf*16 + col; \
      int byt = (rr*256 + kc*64 + g*16) ^ ((rr & 7) << 4); \
      af[mf] = *(bf16x8*)(AsB + byt); \
    } \
    _Pragma("unroll") \
    for (int nf = 0; nf < 2; ++nf) { \
      int rr = nbase + nf*16 + col; \
      int byt = (rr*256 + kc*64 + g*16) ^ ((rr & 7) << 4); \
      bfr[nf] = *(bf16x8*)(BsB + byt); \
    } \
    _Pragma("unroll") \
    for (int mf = 0; mf < 4; ++mf) \
      _Pragma("unroll") \
      for (int nf = 0; nf < 2; ++nf) \
        accv[mf][nf] = __builtin_amdgcn_mfma_f32_16x16x32_bf16(af[mf], bfr[nf], accv[mf][nf], 0, 0, 0); \
  } \
} while(0)

#define LN_REDUCE(accv) do { \
  _Pragma("unroll") \
  for (int mf = 0; mf < 4; ++mf) { \
    _Pragma("unroll") \
    for (int r = 0; r < 4; ++r) { \
      float s1 = accv[mf][0][r] + accv[mf][1][r]; \
      float s2 = accv[mf][0][r]*accv[mf][0][r] + accv[mf][1][r]*accv[mf][1][r]; \
      _Pragma("unroll") \
      for (int o = 1; o <= 8; o <<= 1) { s1 += __shfl_xor(s1, o); s2 += __shfl_xor(s2, o); } \
      if (col == 0) { int rL = mbase + mf*16 + g*4 + r; redP[0][wn][rL] = s1; redP[1][wn][rL] = s2; } \
    } \
  } \
  __syncthreads(); \
  if (t < 128) { \
    float s1 = redP[0][0][t] + redP[0][1][t] + redP[0][2][t] + redP[0][3][t]; \
    float s2 = redP[1][0][t] + redP[1][1][t] + redP[1][2][t] + redP[1][3][t]; \
    float mu_ = s1 * (1.f/DIM); \
    float var_ = s2 * (1.f/DIM) - mu_*mu_; \
    muA[t] = mu_; invA[t] = 1.f / sqrtf(var_ + 1e-8f); \
  } \
  __syncthreads(); \
} while(0)

// QKV projection: grid (2, N/128). x==0 -> Q from lnq (scaled 1/8);
// x==1 -> K and V from seqs, staging seqs once and looping 2 weight panels.
__global__ __launch_bounds__(512) void qkv_kernel(
    const short* __restrict__ lnq, const short* __restrict__ seqs,
    const short* __restrict__ Wb, const float* __restrict__ bias,
    short* __restrict__ C){
  __shared__ short As[16384];
  __shared__ short Bs[16384];
  char* AsB = (char*)As; char* BsB = (char*)Bs;
  const int row0 = blockIdx.y * 128;
  const int t = threadIdx.x;
  const bool isQ = (blockIdx.x == 0);
  const short* Ap = isQ ? lnq : seqs;
  const int npan = isQ ? 1 : 2;
  const int colbase = isQ ? 0 : 128;

  // stage A once
  #pragma unroll
  for (int i = 0; i < 4; ++i) {
    int flat = t*8 + i*4096;
    int rr = flat >> 7, cc = flat & 127;
    bf16x8 a8 = *(const bf16x8*)(Ap + (size_t)(row0 + rr)*128 + cc);
    int byt = (rr*256 + cc*2) ^ ((rr & 7) << 4);
    *(bf16x8*)(AsB + byt) = a8;
  }

  const int w = t >> 6, l = t & 63;
  const int wm = w >> 2, wn = w & 3;
  const int col = l & 15, g = l >> 4;
  const int mbase = wm*64, nbase = wn*32;
  const float qs = isQ ? 0.125f : 1.f;

  for (int p = 0; p < npan; ++p) {
    const int col0 = colbase + p*128;
    #pragma unroll
    for (int i = 0; i < 4; ++i) {
      int flat = t*8 + i*4096;
      int rr = flat >> 7, cc = flat & 127;
      bf16x8 b8 = *(const bf16x8*)(Wb + (size_t)(col0 + rr)*128 + cc);
      int byt = (rr*256 + cc*2) ^ ((rr & 7) << 4);
      *(bf16x8*)(BsB + byt) = b8;
    }
    __syncthreads();

    f32x4 acc[4][2];
    #pragma unroll
    for (int mf = 0; mf < 4; ++mf)
      #pragma unroll
      for (int nf = 0; nf < 2; ++nf) { f32x4 z = {0.f,0.f,0.f,0.f}; acc[mf][nf] = z; }
    MLP_MFMA(acc);

    float biasv[2];
    #pragma unroll
    for (int nf = 0; nf < 2; ++nf) biasv[nf] = bias[col0 + nbase + nf*16 + col];
    #pragma unroll
    for (int mf = 0; mf < 4; ++mf)
      #pragma unroll
      for (int r = 0; r < 4; ++r) {
        int rr = row0 + mbase + mf*16 + g*4 + r;
        #pragma unroll
        for (int nf = 0; nf < 2; ++nf) {
          int cc = col0 + nbase + nf*16 + col;
          float v = (acc[mf][nf][r] + biasv[nf]) * qs;
          C[(size_t)rr*384 + cc] = f2bf(v);
        }
      }
    __syncthreads();   // Bs reads done before restage (and harmless last iter)
  }
}

// Fused per-layer MLP block: attnout@Wo+bo+resq -> LN(ffn) -> relu(@W1+b1) -> @W2+b2+x
// -> mask -> (optional C=seqs_next) + LN(lnS2) -> lnOut. One block per 128 rows.
template<int WRITE_C>
__global__ __launch_bounds__(512) void mlp_kernel(
    const short* __restrict__ qkvQ, const short* __restrict__ resq,
    const short* __restrict__ wo_b, const float* __restrict__ bo,
    const float* __restrict__ ffnS, const float* __restrict__ ffnB,
    const short* __restrict__ w1_b, const float* __restrict__ b1,
    const short* __restrict__ w2_b, const float* __restrict__ b2,
    const int* __restrict__ lsq,
    short* __restrict__ C,
    const float* __restrict__ lnS2, const float* __restrict__ lnB2,
    short* __restrict__ lnOut){
  __shared__ short As[16384];
  __shared__ short Bs[16384];
  __shared__ float redP[2][4][128];
  __shared__ float muA[128], invA[128];
  char* AsB = (char*)As; char* BsB = (char*)Bs;
  const int row0 = blockIdx.x * 128;
  const int t = threadIdx.x;

  #pragma unroll
  for (int i = 0; i < 4; ++i) {
    int flat = t*8 + i*4096;
    int rr = flat >> 7, cc = flat & 127;
    bf16x8 a8 = *(const bf16x8*)(qkvQ + (size_t)(row0 + rr)*384 + cc);
    int byt = (rr*256 + cc*2) ^ ((rr & 7) << 4);
    *(bf16x8*)(AsB + byt) = a8;
    bf16x8 b8 = *(const bf16x8*)(wo_b + (size_t)rr*128 + cc);
    *(bf16x8*)(BsB + byt) = b8;
  }
  __syncthreads();

  const int w = t >> 6, l = t & 63;
  const int wm = w >> 2, wn = w & 3;
  const int col = l & 15, g = l >> 4;
  const int mbase = wm*64, nbase = wn*32;

  f32x4 acc[4][2];
  #pragma unroll
  for (int mf = 0; mf < 4; ++mf)
    #pragma unroll
    for (int nf = 0; nf < 2; ++nf) { f32x4 z = {0.f,0.f,0.f,0.f}; acc[mf][nf] = z; }
  MLP_MFMA(acc);

  float bov[2];
  #pragma unroll
  for (int nf = 0; nf < 2; ++nf) bov[nf] = bo[nbase + nf*16 + col];
  #pragma unroll
  for (int mf = 0; mf < 4; ++mf)
    #pragma unroll
    for (int r = 0; r < 4; ++r) {
      int rL = mbase + mf*16 + g*4 + r;
      #pragma unroll
      for (int nf = 0; nf < 2; ++nf) {
        int cL = nbase + nf*16 + col;
        acc[mf][nf][r] += bov[nf] + bf2f(((const unsigned short*)resq)[(size_t)(row0 + rL)*DIM + cL]);
      }
    }
  LN_REDUCE(acc);

  float xv[4][2][4];
  #pragma unroll
  for (int mf = 0; mf < 4; ++mf)
    #pragma unroll
    for (int r = 0; r < 4; ++r) {
      int rL = mbase + mf*16 + g*4 + r;
      float mu = muA[rL], inv = invA[rL];
      #pragma unroll
      for (int nf = 0; nf < 2; ++nf) {
        int cL = nbase + nf*16 + col;
        float lnv = (acc[mf][nf][r] - mu)*inv*ffnS[cL] + ffnB[cL];
        xv[mf][nf][r] = lnv;
        int byt = (rL*256 + cL*2) ^ ((rL & 7) << 4);
        *(short*)(AsB + byt) = f2bf(lnv);
      }
    }
  #pragma unroll
  for (int i = 0; i < 4; ++i) {
    int flat = t*8 + i*4096;
    int rr = flat >> 7, cc = flat & 127;
    bf16x8 b8 = *(const bf16x8*)(w1_b + (size_t)rr*128 + cc);
    int byt = (rr*256 + cc*2) ^ ((rr & 7) << 4);
    *(bf16x8*)(BsB + byt) = b8;
  }
  __syncthreads();

  #pragma unroll
  for (int mf = 0; mf < 4; ++mf)
    #pragma unroll
    for (int nf = 0; nf < 2; ++nf) { f32x4 z = {0.f,0.f,0.f,0.f}; acc[mf][nf] = z; }
  MLP_MFMA(acc);
  __syncthreads();

  float b1v[2];
  #pragma unroll
  for (int nf = 0; nf < 2; ++nf) b1v[nf] = b1[nbase + nf*16 + col];
  #pragma unroll
  for (int mf = 0; mf < 4; ++mf)
    #pragma unroll
    for (int r = 0; r < 4; ++r) {
      int rL = mbase + mf*16 + g*4 + r;
      #pragma unroll
      for (int nf = 0; nf < 2; ++nf) {
        int cL = nbase + nf*16 + col;
        float h = fmaxf(acc[mf][nf][r] + b1v[nf], 0.f);
        int byt = (rL*256 + cL*2) ^ ((rL & 7) << 4);
        *(short*)(AsB + byt) = f2bf(h);
      }
    }
  #pragma unroll
  for (int i = 0; i < 4; ++i) {
    int flat = t*8 + i*4096;
    int rr = flat >> 7, cc = flat & 127;
    bf16x8 b8 = *(const bf16x8*)(w2_b + (size_t)rr*128 + cc);
    int byt = (rr*256 + cc*2) ^ ((rr & 7) << 4);
    *(bf16x8*)(BsB + byt) = b8;
  }
  __syncthreads();

  #pragma unroll
  for (int mf = 0; mf < 4; ++mf)
    #pragma unroll
    for (int nf = 0; nf < 2; ++nf) { f32x4 z = {0.f,0.f,0.f,0.f}; acc[mf][nf] = z; }
  MLP_MFMA(acc);

  float b2v[2];
  #pragma unroll
  for (int nf = 0; nf < 2; ++nf) b2v[nf] = b2[nbase + nf*16 + col];
  #pragma unroll
  for (int mf = 0; mf < 4; ++mf)
    #pragma unroll
    for (int r = 0; r < 4; ++r) {
      int rL = mbase + mf*16 + g*4 + r;
      bool zr = (lsq[row0 + rL] == 0);
      #pragma unroll
      for (int nf = 0; nf < 2; ++nf) {
        float v = acc[mf][nf][r] + b2v[nf] + xv[mf][nf][r];
        if (zr) v = 0.f;
        acc[mf][nf][r] = v;
      }
    }
  LN_REDUCE(acc);
  #pragma unroll
  for (int mf = 0; mf < 4; ++mf)
    #pragma unroll
    for (int r = 0; r < 4; ++r) {
      int rL = mbase + mf*16 + g*4 + r;
      float mu = muA[rL], inv = invA[rL];
      #pragma unroll
      for (int nf = 0; nf < 2; ++nf) {
        int cL = nbase + nf*16 + col;
        float v = acc[mf][nf][r];
        float lnv = (v - mu)*inv*lnS2[cL] + lnB2[cL];
        lnOut[(size_t)(row0 + rL)*DIM + cL] = f2bf(lnv);
        if (WRITE_C) C[(size_t)(row0 + rL)*DIM + cL] = f2bf(v);
      }
    }
}

// MFMA causal attention, bf16 qkv, causal tile-skip + balanced wave->qtile pairing.
__global__ __launch_bounds__(512) void attn_kernel(short* __restrict__ qkv){
  __shared__ short Ks[224*64];
  __shared__ short Vt[64*224];
  __shared__ short Ps[8][16*232];
  const int b = blockIdx.x >> 1, h = blockIdx.x & 1;
  short* base = qkv + (size_t)b*L_SEQ*384 + h*64;
  const short* baseK = base + 128;
  const short* baseV = base + 256;
  const int t = threadIdx.x;
  char* KsB = (char*)Ks;
  char* VtB = (char*)Vt;

  for (int idx = t; idx < 224*8; idx += 512) {
    int row = idx >> 3, c8 = idx & 7;
    bf16x8 kv = {0,0,0,0,0,0,0,0}, vv = {0,0,0,0,0,0,0,0};
    if (row < L_SEQ) {
      kv = *(const bf16x8*)(baseK + (size_t)row*384 + c8*8);
      vv = *(const bf16x8*)(baseV + (size_t)row*384 + c8*8);
    }
    int kbyte = (row*128 + c8*16) ^ ((row & 7) << 4);
    *(bf16x8*)(KsB + kbyte) = kv;
    #pragma unroll
    for (int e = 0; e < 8; ++e) {
      int d = c8*8 + e;
      int vbyte = (d*448 + row*2) ^ ((d & 7) << 4);
      *(short*)(VtB + vbyte) = vv[e];
    }
  }
  __syncthreads();

  const int w = t >> 6, l = t & 63;
  const int col = l & 15, g = l >> 4, g4 = g * 4;
  char* PB = (char*)Ps[w];

  const int ntiles = (w < 5) ? 2 : 1;
  for (int j = 0; j < ntiles; ++j) {
    const int qt = (j == 0) ? w : 12 - w;
    bf16x8 qf[2];
    {
      int gr = qt*16 + col;
      #pragma unroll
      for (int c = 0; c < 2; ++c) {
        bf16x8 q = {0,0,0,0,0,0,0,0};
        if (gr < L_SEQ) q = *(const bf16x8*)(base + (size_t)gr*384 + c*32 + g*8);
        qf[c] = q;
      }
    }
    f32x4 sc[13];
    #pragma unroll
    for (int kt = 0; kt < 13; ++kt) {
      if (kt <= qt) {
        f32x4 a = {0.f,0.f,0.f,0.f};
        #pragma unroll
        for (int c = 0; c < 2; ++c) {
          int row = kt*16 + col;
          int byt = (row*128 + c*64 + g*16) ^ ((row & 7) << 4);
          bf16x8 kf = *(bf16x8*)(KsB + byt);
          a = __builtin_amdgcn_mfma_f32_16x16x32_bf16(qf[c], kf, a, 0, 0, 0);
        }
        sc[kt] = a;
      }
    }
    float m[4] = {-1e30f,-1e30f,-1e30f,-1e30f};
    #pragma unroll
    for (int kt = 0; kt < 13; ++kt) {
      if (kt <= qt) {
        #pragma unroll
        for (int r = 0; r < 4; ++r) {
          bool ok = (kt < qt) || (col <= g4 + r);
          if (!ok) sc[kt][r] = -1e30f;
          m[r] = fmaxf(m[r], sc[kt][r]);
        }
      }
    }
    #pragma unroll
    for (int r = 0; r < 4; ++r) {
      #pragma unroll
      for (int o = 1; o <= 8; o <<= 1) m[r] = fmaxf(m[r], __shfl_xor(m[r], o));
    }
    float s[4] = {0.f,0.f,0.f,0.f};
    #pragma unroll
    for (int kt = 0; kt < 13; ++kt) {
      if (kt <= qt) {
        #pragma unroll
        for (int r = 0; r < 4; ++r) {
          float e = __expf(sc[kt][r] - m[r]);
          sc[kt][r] = e;
          s[r] += e;
        }
      }
    }
    float inv[4];
    #pragma unroll
    for (int r = 0; r < 4; ++r) {
      #pragma unroll
      for (int o = 1; o <= 8; o <<= 1) s[r] += __shfl_xor(s[r], o);
      inv[r] = 1.f / s[r];
    }
    #pragma unroll
    for (int kt = 0; kt < 13; ++kt) {
      if (kt <= qt) {
        #pragma unroll
        for (int r = 0; r < 4; ++r)
          *(short*)(PB + ((g4 + r)*232 + kt*16 + col)*2) = f2bf(sc[kt][r]);
      } else if (kt == qt + 1) {
        #pragma unroll
        for (int r = 0; r < 4; ++r)
          *(short*)(PB + ((g4 + r)*232 + kt*16 + col)*2) = 0;
      }
    }
    #pragma unroll
    for (int r = 0; r < 4; ++r)
      *(short*)(PB + ((g4 + r)*232 + 208 + col)*2) = 0;
    asm volatile("s_waitcnt lgkmcnt(0)" ::: "memory");
    f32x4 o4[4];
    #pragma unroll
    for (int nt = 0; nt < 4; ++nt) { f32x4 z = {0.f,0.f,0.f,0.f}; o4[nt] = z; }
    const int kcmax = (qt*16 + 15) >> 5;
    #pragma unroll
    for (int kc = 0; kc < 7; ++kc) {
      if (kc <= kcmax) {
        bf16x8 pf = *(bf16x8*)(PB + col*464 + kc*64 + g*16);
        #pragma unroll
        for (int nt = 0; nt < 4; ++nt) {
          int d = nt*16 + col;
          int byt = (d*448 + kc*64 + g*16) ^ ((d & 7) << 4);
          bf16x8 vf = *(bf16x8*)(VtB + byt);
          o4[nt] = __builtin_amdgcn_mfma_f32_16x16x32_bf16(pf, vf, o4[nt], 0, 0, 0);
        }
      }
    }
    #pragma unroll
    for (int nt = 0; nt < 4; ++nt)
      #pragma unroll
      for (int r = 0; r < 4; ++r) {
        int qr = qt*16 + g4 + r;
        if (qr < L_SEQ) base[(size_t)qr*384 + nt*16 + col] = f2bf(o4[nt][r] * inv[r]);
      }
  }
}

// out = feats + LN(nbr_agg + qn). 2 rows per wave; gather-then-reduce.
__global__ __launch_bounds__(256) void final_kernel(
    const short* __restrict__ feats_b, const short* __restrict__ qn_b,
    const int* __restrict__ nbr, const short* __restrict__ user_b,
    const float* __restrict__ is_, const float* __restrict__ ib,
    float* __restrict__ out){
  int wave = threadIdx.x >> 6, lane = threadIdx.x & 63;
  int half = lane >> 5, sl = lane & 31;
  size_t r = (size_t)blockIdx.x*8 + wave*2 + half;

  int idxs[10];
  #pragma unroll
  for (int n = 0; n < 10; ++n) idxs[n] = nbr[r*10 + n];
  ushort4 kv4[10];
  #pragma unroll
  for (int n = 0; n < 10; ++n)
    kv4[n] = ((const ushort4*)(user_b + (size_t)idxs[n]*DIM))[sl];
  ushort4 fv = ((const ushort4*)(feats_b + r*DIM))[sl];
  ushort4 qv4 = ((const ushort4*)(qn_b + r*DIM))[sl];

  float q0 = bf2f(qv4.x), q1 = bf2f(qv4.y), q2 = bf2f(qv4.z), q3 = bf2f(qv4.w);
  float kn[10][4]; float scn[10];
  #pragma unroll
  for (int n = 0; n < 10; ++n) {
    kn[n][0] = bf2f(kv4[n].x); kn[n][1] = bf2f(kv4[n].y);
    kn[n][2] = bf2f(kv4[n].z); kn[n][3] = bf2f(kv4[n].w);
    float p = q0*kn[n][0] + q1*kn[n][1] + q2*kn[n][2] + q3*kn[n][3];
    #pragma unroll
    for (int o = 1; o <= 16; o <<= 1) p += __shfl_xor(p, o);
    scn[n] = idxs[n] ? p * 0.08838834764831845f : -1.0e9f;
  }
  float m = scn[0];
  #pragma unroll
  for (int n = 1; n < 10; ++n) m = fmaxf(m, scn[n]);
  float w[10], sum = 0.f;
  #pragma unroll
  for (int n = 0; n < 10; ++n) { w[n] = expf(scn[n] - m); sum += w[n]; }
  float invs = 1.f / sum;
  float a0 = 0.f, a1 = 0.f, a2 = 0.f, a3 = 0.f;
  #pragma unroll
  for (int n = 0; n < 10; ++n) {
    a0 += w[n]*kn[n][0]; a1 += w[n]*kn[n][1]; a2 += w[n]*kn[n][2]; a3 += w[n]*kn[n][3];
  }
  a0 = a0*invs + q0;
  a1 = a1*invs + q1;
  a2 = a2*invs + q2;
  a3 = a3*invs + q3;
  float s1 = a0 + a1 + a2 + a3;
  #pragma unroll
  for (int o = 1; o <= 16; o <<= 1) s1 += __shfl_xor(s1, o);
  float mu2 = s1 * (1.f/DIM);
  float d0 = a0 - mu2, d1 = a1 - mu2, d2 = a2 - mu2, d3 = a3 - mu2;
  float sq = d0*d0 + d1*d1 + d2*d2 + d3*d3;
  #pragma unroll
  for (int o = 1; o <= 16; o <<= 1) sq += __shfl_xor(sq, o);
  float inv2 = 1.f / sqrtf(sq * (1.f/DIM) + 1e-8f);
  float f0 = bf2f(fv.x), f1 = bf2f(fv.y), f2 = bf2f(fv.z), f3 = bf2f(fv.w);
  float4 isc = ((const float4*)is_)[sl], ibc = ((const float4*)ib)[sl];
  float4 o;
  o.x = f0 + d0*inv2*isc.x + ibc.x;
  o.y = f1 + d1*inv2*isc.y + ibc.y;
  o.z = f2 + d2*inv2*isc.z + ibc.z;
  o.w = f3 + d3*inv2*isc.w + ibc.w;
  ((float4*)(out + r*DIM))[sl] = o;
}

extern "C" void kernel_launch(void* const* d_in, const int* in_sizes, int n_in,
                              void* d_out, int out_size, void* d_ws, size_t ws_size,
                              hipStream_t stream) {
  const int*   lsq    = (const int*)d_in[0];
  const int*   nbr    = (const int*)d_in[1];
  const float* item   = (const float*)d_in[2];
  const float* user   = (const float*)d_in[3];
  const float* pos    = (const float*)d_in[4];
  const float* attn_s = (const float*)d_in[5];
  const float* attn_b = (const float*)d_in[6];
  const float* Wqkv   = (const float*)d_in[7];
  const float* bqkv   = (const float*)d_in[8];
  const float* Wo     = (const float*)d_in[9];
  const float* bo     = (const float*)d_in[10];
  const float* ffn_s  = (const float*)d_in[11];
  const float* ffn_b  = (const float*)d_in[12];
  const float* W1     = (const float*)d_in[13];
  const float* b1     = (const float*)d_in[14];
  const float* W2     = (const float*)d_in[15];
  const float* b2     = (const float*)d_in[16];
  const float* last_s = (const float*)d_in[17];
  const float* last_b = (const float*)d_in[18];
  const float* iui_s  = (const float*)d_in[19];
  const float* iui_b  = (const float*)d_in[20];
  float* out = (float*)d_out;

  const int N = NROWS;  // 51200 rows
  short* seqs_b = (short*)d_ws;                       // N x 128 bf16
  short* lnq_b  = seqs_b + (size_t)N*DIM;             // N x 128 bf16
  short* qkv_b  = lnq_b  + (size_t)N*DIM;             // N x 384 bf16
  short* wqkv_b = qkv_b  + (size_t)N*384;             // 2 x 384 x 128
  short* wo_b   = wqkv_b + 2*384*128;
  short* w1_b   = wo_b   + 2*128*128;
  short* w2_b   = w1_b   + 2*128*128;
  short* user_b = w2_b   + 2*128*128;                 // 50001 x 128 bf16
  short* qn_b   = user_b + (size_t)50001*DIM + 64;    // N x 128 bf16

  prep_kernel<<<WBLK + UBLK + EBLK, 256, 0, stream>>>(
      Wqkv, Wo, W1, W2, wqkv_b,
      user, user_b,
      lsq, item, pos, attn_s, attn_b,
      seqs_b, lnq_b, qn_b);

  for (int i = 0; i < 2; ++i) {
    qkv_kernel<<<dim3(2, N/128), 512, 0, stream>>>(
        lnq_b, seqs_b, wqkv_b + (size_t)i*384*128, bqkv + i*384, qkv_b);
    attn_kernel<<<256*2, 512, 0, stream>>>(qkv_b);
    if (i == 0) {
      mlp_kernel<1><<<N/128, 512, 0, stream>>>(
          qkv_b, lnq_b, wo_b, bo, ffn_s, ffn_b,
          w1_b, b1, w2_b, b2, lsq,
          seqs_b, attn_s + DIM, attn_b + DIM, lnq_b);
    } else {
      mlp_kernel<0><<<N/128, 512, 0, stream>>>(
          qkv_b, lnq_b, wo_b + 128*128, bo + DIM, ffn_s + DIM, ffn_b + DIM,
          w1_b + 128*128, b1 + DIM, w2_b + 128*128, b2 + DIM, lsq,
          nullptr, last_s, last_b, lnq_b);
    }
  }

  final_kernel<<<N/8, 256, 0, stream>>>(lnq_b, qn_b, nbr, user_b,
                                        iui_s, iui_b, out);
}

// Round 13
// 203.441 us; speedup vs baseline: 1.0906x; 1.0906x over previous
//
#include <hip/hip_runtime.h>
#include <hip/hip_bf16.h>

#define L_SEQ 200
#define DIM 128
#define NROWS (256*200)

#define W4 49152                 // weight float4 count
#define U4 (50001*DIM/4)         // user-table float4 count (1600032)
#define WBLK 192
#define UBLK ((U4 + 255)/256)    // 6251
#define EBLK (NROWS/4)           // 12800

typedef __attribute__((ext_vector_type(8))) short bf16x8;
typedef __attribute__((ext_vector_type(4))) float f32x4;

__device__ __forceinline__ float wave_sum(float v){
  #pragma unroll
  for (int o = 32; o; o >>= 1) v += __shfl_xor(v, o);
  return v;
}
__device__ __forceinline__ short f2bf(float f){
  union { float f; unsigned u; } x; x.f = f;
  unsigned r = x.u + 0x7fffu + ((x.u >> 16) & 1u);
  return (short)(r >> 16);
}
__device__ __forceinline__ float bf2f(unsigned short u){
  union { unsigned u; float f; } x; x.u = ((unsigned)u) << 16;
  return x.f;
}

// One launch: weight cvt (blocks 0..191), user-table cvt (next 6251),
// embed+LN (last 12800). All sections independent.
__global__ __launch_bounds__(256) void prep_kernel(
    const float* __restrict__ Wqkv, const float* __restrict__ Wo,
    const float* __restrict__ W1, const float* __restrict__ W2,
    short* __restrict__ wdst,
    const float* __restrict__ user, short* __restrict__ user_b,
    const int* __restrict__ lsq, const float* __restrict__ item,
    const float* __restrict__ pos,
    const float* __restrict__ s, const float* __restrict__ b,
    short* __restrict__ seqs_b, short* __restrict__ lnq_b, short* __restrict__ qn_b){
  int bid = blockIdx.x;
  if (bid < WBLK) {
    int i = bid*256 + threadIdx.x;
    if (i < W4) {
      const float* src; int off;
      if (i < 24576)      { src = Wqkv; off = i; }
      else if (i < 32768) { src = Wo;   off = i - 24576; }
      else if (i < 40960) { src = W1;   off = i - 32768; }
      else                { src = W2;   off = i - 40960; }
      float4 v = ((const float4*)src)[off];
      short4 sv; sv.x = f2bf(v.x); sv.y = f2bf(v.y); sv.z = f2bf(v.z); sv.w = f2bf(v.w);
      ((short4*)wdst)[i] = sv;
    }
    return;
  }
  bid -= WBLK;
  if (bid < UBLK) {
    int i = bid*256 + threadIdx.x;
    if (i < U4) {
      float4 v = ((const float4*)user)[i];
      short4 sv; sv.x = f2bf(v.x); sv.y = f2bf(v.y); sv.z = f2bf(v.z); sv.w = f2bf(v.w);
      ((short4*)user_b)[i] = sv;
    }
    return;
  }
  bid -= UBLK;
  // embed + LN: 4 waves, one row each
  int wave = threadIdx.x >> 6, lane = threadIdx.x & 63;
  size_t r = (size_t)bid*4 + wave;
  int it = lsq[r];
  float2 iv = ((const float2*)(item + (size_t)it*DIM))[lane];
  float2 p = ((const float2*)(pos + (r % L_SEQ)*DIM))[lane];
  short2 qv; qv.x = f2bf(iv.x); qv.y = f2bf(iv.y);
  ((short2*)(qn_b + r*DIM))[lane] = qv;
  float vx = 0.f, vy = 0.f;
  if (it) {
    vx = iv.x * 11.313708498984761f + p.x;
    vy = iv.y * 11.313708498984761f + p.y;
  }
  short2 sv; sv.x = f2bf(vx); sv.y = f2bf(vy);
  ((short2*)(seqs_b + r*DIM))[lane] = sv;
  float mu = wave_sum(vx + vy) * (1.f/DIM);
  float dx = vx - mu, dy = vy - mu;
  float var = wave_sum(dx*dx + dy*dy) * (1.f/DIM);
  float inv = 1.f / sqrtf(var + 1e-8f);
  float2 sc = ((const float2*)s)[lane];
  float2 bc = ((const float2*)b)[lane];
  short2 ov; ov.x = f2bf(dx*inv*sc.x + bc.x); ov.y = f2bf(dy*inv*sc.y + bc.y);
  ((short2*)(lnq_b + r*DIM))[lane] = ov;
}

#define MLP_MFMA(accv) do { \
  _Pragma("unroll") \
  for (int kc = 0; kc < 4; ++kc) { \
    bf16x8 af[4], bfr[2]; \
    _Pragma("unroll") \
    for (int mf = 0; mf < 4; ++mf) { \
      int rr = mbase + mf*16 + col; \
      int byt = (rr*256 + kc*64 + g*16) ^ ((rr & 7) << 4); \
      af[mf] = *(bf16x8*)(AsB + byt); \
    } \
    _Pragma("unroll") \
    for (int nf = 0; nf < 2; ++nf) { \
      int rr = nbase + nf*16 + col; \
      int byt = (rr*256 + kc*64 + g*16) ^ ((rr & 7) << 4); \
      bfr[nf] = *(bf16x8*)(BsB + byt); \
    } \
    _Pragma("unroll") \
    for (int mf = 0; mf < 4; ++mf) \
      _Pragma("unroll") \
      for (int nf = 0; nf < 2; ++nf) \
        accv[mf][nf] = __builtin_amdgcn_mfma_f32_16x16x32_bf16(af[mf], bfr[nf], accv[mf][nf], 0, 0, 0); \
  } \
} while(0)

#define LN_REDUCE(accv) do { \
  _Pragma("unroll") \
  for (int mf = 0; mf < 4; ++mf) { \
    _Pragma("unroll") \
    for (int r = 0; r < 4; ++r) { \
      float s1 = accv[mf][0][r] + accv[mf][1][r]; \
      float s2 = accv[mf][0][r]*accv[mf][0][r] + accv[mf][1][r]*accv[mf][1][r]; \
      _Pragma("unroll") \
      for (int o = 1; o <= 8; o <<= 1) { s1 += __shfl_xor(s1, o); s2 += __shfl_xor(s2, o); } \
      if (col == 0) { int rL = mbase + mf*16 + g*4 + r; redP[0][wn][rL] = s1; redP[1][wn][rL] = s2; } \
    } \
  } \
  __syncthreads(); \
  if (t < 128) { \
    float s1 = redP[0][0][t] + redP[0][1][t] + redP[0][2][t] + redP[0][3][t]; \
    float s2 = redP[1][0][t] + redP[1][1][t] + redP[1][2][t] + redP[1][3][t]; \
    float mu_ = s1 * (1.f/DIM); \
    float var_ = s2 * (1.f/DIM) - mu_*mu_; \
    muA[t] = mu_; invA[t] = 1.f / sqrtf(var_ + 1e-8f); \
  } \
  __syncthreads(); \
} while(0)

// QKV projection: grid (3, N/128). x==0 -> Q from lnq (scaled 1/8), x=1,2 -> K,V from seqs.
__global__ __launch_bounds__(512) void qkv_kernel(
    const short* __restrict__ lnq, const short* __restrict__ seqs,
    const short* __restrict__ Wb, const float* __restrict__ bias,
    short* __restrict__ C){
  __shared__ short As[16384];
  __shared__ short Bs[16384];
  char* AsB = (char*)As; char* BsB = (char*)Bs;
  const int row0 = blockIdx.y * 128, col0 = blockIdx.x * 128;
  const int t = threadIdx.x;
  const short* Ap = (blockIdx.x == 0) ? lnq : seqs;

  #pragma unroll
  for (int i = 0; i < 4; ++i) {
    int flat = t*8 + i*4096;
    int rr = flat >> 7, cc = flat & 127;
    bf16x8 a8 = *(const bf16x8*)(Ap + (size_t)(row0 + rr)*128 + cc);
    int byt = (rr*256 + cc*2) ^ ((rr & 7) << 4);
    *(bf16x8*)(AsB + byt) = a8;
    bf16x8 b8 = *(const bf16x8*)(Wb + (size_t)(col0 + rr)*128 + cc);
    *(bf16x8*)(BsB + byt) = b8;
  }
  __syncthreads();

  const int w = t >> 6, l = t & 63;
  const int wm = w >> 2, wn = w & 3;
  const int col = l & 15, g = l >> 4;
  const int mbase = wm*64, nbase = wn*32;

  f32x4 acc[4][2];
  #pragma unroll
  for (int mf = 0; mf < 4; ++mf)
    #pragma unroll
    for (int nf = 0; nf < 2; ++nf) { f32x4 z = {0.f,0.f,0.f,0.f}; acc[mf][nf] = z; }
  MLP_MFMA(acc);

  float biasv[2];
  #pragma unroll
  for (int nf = 0; nf < 2; ++nf) biasv[nf] = bias[col0 + nbase + nf*16 + col];
  const float qs = (blockIdx.x == 0) ? 0.125f : 1.f;
  #pragma unroll
  for (int mf = 0; mf < 4; ++mf)
    #pragma unroll
    for (int r = 0; r < 4; ++r) {
      int rr = row0 + mbase + mf*16 + g*4 + r;
      #pragma unroll
      for (int nf = 0; nf < 2; ++nf) {
        int cc = col0 + nbase + nf*16 + col;
        float v = (acc[mf][nf][r] + biasv[nf]) * qs;
        C[(size_t)rr*384 + cc] = f2bf(v);
      }
    }
}

// Fused per-layer MLP block: attnout@Wo+bo+resq -> LN(ffn) -> relu(@W1+b1) -> @W2+b2+x
// -> mask -> (optional C=seqs_next) + LN(lnS2) -> lnOut. One block per 128 rows.
template<int WRITE_C>
__global__ __launch_bounds__(512) void mlp_kernel(
    const short* __restrict__ qkvQ, const short* __restrict__ resq,
    const short* __restrict__ wo_b, const float* __restrict__ bo,
    const float* __restrict__ ffnS, const float* __restrict__ ffnB,
    const short* __restrict__ w1_b, const float* __restrict__ b1,
    const short* __restrict__ w2_b, const float* __restrict__ b2,
    const int* __restrict__ lsq,
    short* __restrict__ C,
    const float* __restrict__ lnS2, const float* __restrict__ lnB2,
    short* __restrict__ lnOut){
  __shared__ short As[16384];
  __shared__ short Bs[16384];
  __shared__ float redP[2][4][128];
  __shared__ float muA[128], invA[128];
  char* AsB = (char*)As; char* BsB = (char*)Bs;
  const int row0 = blockIdx.x * 128;
  const int t = threadIdx.x;

  #pragma unroll
  for (int i = 0; i < 4; ++i) {
    int flat = t*8 + i*4096;
    int rr = flat >> 7, cc = flat & 127;
    bf16x8 a8 = *(const bf16x8*)(qkvQ + (size_t)(row0 + rr)*384 + cc);
    int byt = (rr*256 + cc*2) ^ ((rr & 7) << 4);
    *(bf16x8*)(AsB + byt) = a8;
    bf16x8 b8 = *(const bf16x8*)(wo_b + (size_t)rr*128 + cc);
    *(bf16x8*)(BsB + byt) = b8;
  }
  __syncthreads();

  const int w = t >> 6, l = t & 63;
  const int wm = w >> 2, wn = w & 3;
  const int col = l & 15, g = l >> 4;
  const int mbase = wm*64, nbase = wn*32;

  f32x4 acc[4][2];
  #pragma unroll
  for (int mf = 0; mf < 4; ++mf)
    #pragma unroll
    for (int nf = 0; nf < 2; ++nf) { f32x4 z = {0.f,0.f,0.f,0.f}; acc[mf][nf] = z; }
  MLP_MFMA(acc);

  float bov[2];
  #pragma unroll
  for (int nf = 0; nf < 2; ++nf) bov[nf] = bo[nbase + nf*16 + col];
  #pragma unroll
  for (int mf = 0; mf < 4; ++mf)
    #pragma unroll
    for (int r = 0; r < 4; ++r) {
      int rL = mbase + mf*16 + g*4 + r;
      #pragma unroll
      for (int nf = 0; nf < 2; ++nf) {
        int cL = nbase + nf*16 + col;
        acc[mf][nf][r] += bov[nf] + bf2f(((const unsigned short*)resq)[(size_t)(row0 + rL)*DIM + cL]);
      }
    }
  LN_REDUCE(acc);

  float xv[4][2][4];
  #pragma unroll
  for (int mf = 0; mf < 4; ++mf)
    #pragma unroll
    for (int r = 0; r < 4; ++r) {
      int rL = mbase + mf*16 + g*4 + r;
      float mu = muA[rL], inv = invA[rL];
      #pragma unroll
      for (int nf = 0; nf < 2; ++nf) {
        int cL = nbase + nf*16 + col;
        float lnv = (acc[mf][nf][r] - mu)*inv*ffnS[cL] + ffnB[cL];
        xv[mf][nf][r] = lnv;
        int byt = (rL*256 + cL*2) ^ ((rL & 7) << 4);
        *(short*)(AsB + byt) = f2bf(lnv);
      }
    }
  #pragma unroll
  for (int i = 0; i < 4; ++i) {
    int flat = t*8 + i*4096;
    int rr = flat >> 7, cc = flat & 127;
    bf16x8 b8 = *(const bf16x8*)(w1_b + (size_t)rr*128 + cc);
    int byt = (rr*256 + cc*2) ^ ((rr & 7) << 4);
    *(bf16x8*)(BsB + byt) = b8;
  }
  __syncthreads();

  #pragma unroll
  for (int mf = 0; mf < 4; ++mf)
    #pragma unroll
    for (int nf = 0; nf < 2; ++nf) { f32x4 z = {0.f,0.f,0.f,0.f}; acc[mf][nf] = z; }
  MLP_MFMA(acc);
  __syncthreads();

  float b1v[2];
  #pragma unroll
  for (int nf = 0; nf < 2; ++nf) b1v[nf] = b1[nbase + nf*16 + col];
  #pragma unroll
  for (int mf = 0; mf < 4; ++mf)
    #pragma unroll
    for (int r = 0; r < 4; ++r) {
      int rL = mbase + mf*16 + g*4 + r;
      #pragma unroll
      for (int nf = 0; nf < 2; ++nf) {
        int cL = nbase + nf*16 + col;
        float h = fmaxf(acc[mf][nf][r] + b1v[nf], 0.f);
        int byt = (rL*256 + cL*2) ^ ((rL & 7) << 4);
        *(short*)(AsB + byt) = f2bf(h);
      }
    }
  #pragma unroll
  for (int i = 0; i < 4; ++i) {
    int flat = t*8 + i*4096;
    int rr = flat >> 7, cc = flat & 127;
    bf16x8 b8 = *(const bf16x8*)(w2_b + (size_t)rr*128 + cc);
    int byt = (rr*256 + cc*2) ^ ((rr & 7) << 4);
    *(bf16x8*)(BsB + byt) = b8;
  }
  __syncthreads();

  #pragma unroll
  for (int mf = 0; mf < 4; ++mf)
    #pragma unroll
    for (int nf = 0; nf < 2; ++nf) { f32x4 z = {0.f,0.f,0.f,0.f}; acc[mf][nf] = z; }
  MLP_MFMA(acc);

  float b2v[2];
  #pragma unroll
  for (int nf = 0; nf < 2; ++nf) b2v[nf] = b2[nbase + nf*16 + col];
  #pragma unroll
  for (int mf = 0; mf < 4; ++mf)
    #pragma unroll
    for (int r = 0; r < 4; ++r) {
      int rL = mbase + mf*16 + g*4 + r;
      bool zr = (lsq[row0 + rL] == 0);
      #pragma unroll
      for (int nf = 0; nf < 2; ++nf) {
        float v = acc[mf][nf][r] + b2v[nf] + xv[mf][nf][r];
        if (zr) v = 0.f;
        acc[mf][nf][r] = v;
      }
    }
  LN_REDUCE(acc);
  #pragma unroll
  for (int mf = 0; mf < 4; ++mf)
    #pragma unroll
    for (int r = 0; r < 4; ++r) {
      int rL = mbase + mf*16 + g*4 + r;
      float mu = muA[rL], inv = invA[rL];
      #pragma unroll
      for (int nf = 0; nf < 2; ++nf) {
        int cL = nbase + nf*16 + col;
        float v = acc[mf][nf][r];
        float lnv = (v - mu)*inv*lnS2[cL] + lnB2[cL];
        lnOut[(size_t)(row0 + rL)*DIM + cL] = f2bf(lnv);
        if (WRITE_C) C[(size_t)(row0 + rL)*DIM + cL] = f2bf(v);
      }
    }
}

// MFMA causal attention, bf16 qkv, causal tile-skip + balanced wave->qtile pairing.
__global__ __launch_bounds__(512) void attn_kernel(short* __restrict__ qkv){
  __shared__ short Ks[224*64];
  __shared__ short Vt[64*224];
  __shared__ short Ps[8][16*232];
  const int b = blockIdx.x >> 1, h = blockIdx.x & 1;
  short* base = qkv + (size_t)b*L_SEQ*384 + h*64;
  const short* baseK = base + 128;
  const short* baseV = base + 256;
  const int t = threadIdx.x;
  char* KsB = (char*)Ks;
  char* VtB = (char*)Vt;

  for (int idx = t; idx < 224*8; idx += 512) {
    int row = idx >> 3, c8 = idx & 7;
    bf16x8 kv = {0,0,0,0,0,0,0,0}, vv = {0,0,0,0,0,0,0,0};
    if (row < L_SEQ) {
      kv = *(const bf16x8*)(baseK + (size_t)row*384 + c8*8);
      vv = *(const bf16x8*)(baseV + (size_t)row*384 + c8*8);
    }
    int kbyte = (row*128 + c8*16) ^ ((row & 7) << 4);
    *(bf16x8*)(KsB + kbyte) = kv;
    #pragma unroll
    for (int e = 0; e < 8; ++e) {
      int d = c8*8 + e;
      int vbyte = (d*448 + row*2) ^ ((d & 7) << 4);
      *(short*)(VtB + vbyte) = vv[e];
    }
  }
  __syncthreads();

  const int w = t >> 6, l = t & 63;
  const int col = l & 15, g = l >> 4, g4 = g * 4;
  char* PB = (char*)Ps[w];

  const int ntiles = (w < 5) ? 2 : 1;
  for (int j = 0; j < ntiles; ++j) {
    const int qt = (j == 0) ? w : 12 - w;
    bf16x8 qf[2];
    {
      int gr = qt*16 + col;
      #pragma unroll
      for (int c = 0; c < 2; ++c) {
        bf16x8 q = {0,0,0,0,0,0,0,0};
        if (gr < L_SEQ) q = *(const bf16x8*)(base + (size_t)gr*384 + c*32 + g*8);
        qf[c] = q;
      }
    }
    f32x4 sc[13];
    #pragma unroll
    for (int kt = 0; kt < 13; ++kt) {
      if (kt <= qt) {
        f32x4 a = {0.f,0.f,0.f,0.f};
        #pragma unroll
        for (int c = 0; c < 2; ++c) {
          int row = kt*16 + col;
          int byt = (row*128 + c*64 + g*16) ^ ((row & 7) << 4);
          bf16x8 kf = *(bf16x8*)(KsB + byt);
          a = __builtin_amdgcn_mfma_f32_16x16x32_bf16(qf[c], kf, a, 0, 0, 0);
        }
        sc[kt] = a;
      }
    }
    float m[4] = {-1e30f,-1e30f,-1e30f,-1e30f};
    #pragma unroll
    for (int kt = 0; kt < 13; ++kt) {
      if (kt <= qt) {
        #pragma unroll
        for (int r = 0; r < 4; ++r) {
          bool ok = (kt < qt) || (col <= g4 + r);
          if (!ok) sc[kt][r] = -1e30f;
          m[r] = fmaxf(m[r], sc[kt][r]);
        }
      }
    }
    #pragma unroll
    for (int r = 0; r < 4; ++r) {
      #pragma unroll
      for (int o = 1; o <= 8; o <<= 1) m[r] = fmaxf(m[r], __shfl_xor(m[r], o));
    }
    float s[4] = {0.f,0.f,0.f,0.f};
    #pragma unroll
    for (int kt = 0; kt < 13; ++kt) {
      if (kt <= qt) {
        #pragma unroll
        for (int r = 0; r < 4; ++r) {
          float e = __expf(sc[kt][r] - m[r]);
          sc[kt][r] = e;
          s[r] += e;
        }
      }
    }
    float inv[4];
    #pragma unroll
    for (int r = 0; r < 4; ++r) {
      #pragma unroll
      for (int o = 1; o <= 8; o <<= 1) s[r] += __shfl_xor(s[r], o);
      inv[r] = 1.f / s[r];
    }
    #pragma unroll
    for (int kt = 0; kt < 13; ++kt) {
      if (kt <= qt) {
        #pragma unroll
        for (int r = 0; r < 4; ++r)
          *(short*)(PB + ((g4 + r)*232 + kt*16 + col)*2) = f2bf(sc[kt][r]);
      } else if (kt == qt + 1) {
        #pragma unroll
        for (int r = 0; r < 4; ++r)
          *(short*)(PB + ((g4 + r)*232 + kt*16 + col)*2) = 0;
      }
    }
    #pragma unroll
    for (int r = 0; r < 4; ++r)
      *(short*)(PB + ((g4 + r)*232 + 208 + col)*2) = 0;
    asm volatile("s_waitcnt lgkmcnt(0)" ::: "memory");
    f32x4 o4[4];
    #pragma unroll
    for (int nt = 0; nt < 4; ++nt) { f32x4 z = {0.f,0.f,0.f,0.f}; o4[nt] = z; }
    const int kcmax = (qt*16 + 15) >> 5;
    #pragma unroll
    for (int kc = 0; kc < 7; ++kc) {
      if (kc <= kcmax) {
        bf16x8 pf = *(bf16x8*)(PB + col*464 + kc*64 + g*16);
        #pragma unroll
        for (int nt = 0; nt < 4; ++nt) {
          int d = nt*16 + col;
          int byt = (d*448 + kc*64 + g*16) ^ ((d & 7) << 4);
          bf16x8 vf = *(bf16x8*)(VtB + byt);
          o4[nt] = __builtin_amdgcn_mfma_f32_16x16x32_bf16(pf, vf, o4[nt], 0, 0, 0);
        }
      }
    }
    #pragma unroll
    for (int nt = 0; nt < 4; ++nt)
      #pragma unroll
      for (int r = 0; r < 4; ++r) {
        int qr = qt*16 + g4 + r;
        if (qr < L_SEQ) base[(size_t)qr*384 + nt*16 + col] = f2bf(o4[nt][r] * inv[r]);
      }
  }
}

// out = feats + LN(nbr_agg + qn). 2 rows per wave; gather-then-reduce.
__global__ __launch_bounds__(256) void final_kernel(
    const short* __restrict__ feats_b, const short* __restrict__ qn_b,
    const int* __restrict__ nbr, const short* __restrict__ user_b,
    const float* __restrict__ is_, const float* __restrict__ ib,
    float* __restrict__ out){
  int wave = threadIdx.x >> 6, lane = threadIdx.x & 63;
  int half = lane >> 5, sl = lane & 31;
  size_t r = (size_t)blockIdx.x*8 + wave*2 + half;

  int idxs[10];
  #pragma unroll
  for (int n = 0; n < 10; ++n) idxs[n] = nbr[r*10 + n];
  ushort4 kv4[10];
  #pragma unroll
  for (int n = 0; n < 10; ++n)
    kv4[n] = ((const ushort4*)(user_b + (size_t)idxs[n]*DIM))[sl];
  ushort4 fv = ((const ushort4*)(feats_b + r*DIM))[sl];
  ushort4 qv4 = ((const ushort4*)(qn_b + r*DIM))[sl];

  float q0 = bf2f(qv4.x), q1 = bf2f(qv4.y), q2 = bf2f(qv4.z), q3 = bf2f(qv4.w);
  float kn[10][4]; float scn[10];
  #pragma unroll
  for (int n = 0; n < 10; ++n) {
    kn[n][0] = bf2f(kv4[n].x); kn[n][1] = bf2f(kv4[n].y);
    kn[n][2] = bf2f(kv4[n].z); kn[n][3] = bf2f(kv4[n].w);
    float p = q0*kn[n][0] + q1*kn[n][1] + q2*kn[n][2] + q3*kn[n][3];
    #pragma unroll
    for (int o = 1; o <= 16; o <<= 1) p += __shfl_xor(p, o);
    scn[n] = idxs[n] ? p * 0.08838834764831845f : -1.0e9f;
  }
  float m = scn[0];
  #pragma unroll
  for (int n = 1; n < 10; ++n) m = fmaxf(m, scn[n]);
  float w[10], sum = 0.f;
  #pragma unroll
  for (int n = 0; n < 10; ++n) { w[n] = expf(scn[n] - m); sum += w[n]; }
  float invs = 1.f / sum;
  float a0 = 0.f, a1 = 0.f, a2 = 0.f, a3 = 0.f;
  #pragma unroll
  for (int n = 0; n < 10; ++n) {
    a0 += w[n]*kn[n][0]; a1 += w[n]*kn[n][1]; a2 += w[n]*kn[n][2]; a3 += w[n]*kn[n][3];
  }
  a0 = a0*invs + q0;
  a1 = a1*invs + q1;
  a2 = a2*invs + q2;
  a3 = a3*invs + q3;
  float s1 = a0 + a1 + a2 + a3;
  #pragma unroll
  for (int o = 1; o <= 16; o <<= 1) s1 += __shfl_xor(s1, o);
  float mu2 = s1 * (1.f/DIM);
  float d0 = a0 - mu2, d1 = a1 - mu2, d2 = a2 - mu2, d3 = a3 - mu2;
  float sq = d0*d0 + d1*d1 + d2*d2 + d3*d3;
  #pragma unroll
  for (int o = 1; o <= 16; o <<= 1) sq += __shfl_xor(sq, o);
  float inv2 = 1.f / sqrtf(sq * (1.f/DIM) + 1e-8f);
  float f0 = bf2f(fv.x), f1 = bf2f(fv.y), f2 = bf2f(fv.z), f3 = bf2f(fv.w);
  float4 isc = ((const float4*)is_)[sl], ibc = ((const float4*)ib)[sl];
  float4 o;
  o.x = f0 + d0*inv2*isc.x + ibc.x;
  o.y = f1 + d1*inv2*isc.y + ibc.y;
  o.z = f2 + d2*inv2*isc.z + ibc.z;
  o.w = f3 + d3*inv2*isc.w + ibc.w;
  ((float4*)(out + r*DIM))[sl] = o;
}

extern "C" void kernel_launch(void* const* d_in, const int* in_sizes, int n_in,
                              void* d_out, int out_size, void* d_ws, size_t ws_size,
                              hipStream_t stream) {
  const int*   lsq    = (const int*)d_in[0];
  const int*   nbr    = (const int*)d_in[1];
  const float* item   = (const float*)d_in[2];
  const float* user   = (const float*)d_in[3];
  const float* pos    = (const float*)d_in[4];
  const float* attn_s = (const float*)d_in[5];
  const float* attn_b = (const float*)d_in[6];
  const float* Wqkv   = (const float*)d_in[7];
  const float* bqkv   = (const float*)d_in[8];
  const float* Wo     = (const float*)d_in[9];
  const float* bo     = (const float*)d_in[10];
  const float* ffn_s  = (const float*)d_in[11];
  const float* ffn_b  = (const float*)d_in[12];
  const float* W1     = (const float*)d_in[13];
  const float* b1     = (const float*)d_in[14];
  const float* W2     = (const float*)d_in[15];
  const float* b2     = (const float*)d_in[16];
  const float* last_s = (const float*)d_in[17];
  const float* last_b = (const float*)d_in[18];
  const float* iui_s  = (const float*)d_in[19];
  const float* iui_b  = (const float*)d_in[20];
  float* out = (float*)d_out;

  const int N = NROWS;  // 51200 rows
  short* seqs_b = (short*)d_ws;                       // N x 128 bf16
  short* lnq_b  = seqs_b + (size_t)N*DIM;             // N x 128 bf16
  short* qkv_b  = lnq_b  + (size_t)N*DIM;             // N x 384 bf16
  short* wqkv_b = qkv_b  + (size_t)N*384;             // 2 x 384 x 128
  short* wo_b   = wqkv_b + 2*384*128;
  short* w1_b   = wo_b   + 2*128*128;
  short* w2_b   = w1_b   + 2*128*128;
  short* user_b = w2_b   + 2*128*128;                 // 50001 x 128 bf16
  short* qn_b   = user_b + (size_t)50001*DIM + 64;    // N x 128 bf16

  prep_kernel<<<WBLK + UBLK + EBLK, 256, 0, stream>>>(
      Wqkv, Wo, W1, W2, wqkv_b,
      user, user_b,
      lsq, item, pos, attn_s, attn_b,
      seqs_b, lnq_b, qn_b);

  for (int i = 0; i < 2; ++i) {
    qkv_kernel<<<dim3(3, N/128), 512, 0, stream>>>(
        lnq_b, seqs_b, wqkv_b + (size_t)i*384*128, bqkv + i*384, qkv_b);
    attn_kernel<<<256*2, 512, 0, stream>>>(qkv_b);
    if (i == 0) {
      mlp_kernel<1><<<N/128, 512, 0, stream>>>(
          qkv_b, lnq_b, wo_b, bo, ffn_s, ffn_b,
          w1_b, b1, w2_b, b2, lsq,
          seqs_b, attn_s + DIM, attn_b + DIM, lnq_b);
    } else {
      mlp_kernel<0><<<N/128, 512, 0, stream>>>(
          qkv_b, lnq_b, wo_b + 128*128, bo + DIM, ffn_s + DIM, ffn_b + DIM,
          w1_b + 128*128, b1 + DIM, w2_b + 128*128, b2 + DIM, lsq,
          nullptr, last_s, last_b, lnq_b);
    }
  }

  final_kernel<<<N/8, 256, 0, stream>>>(lnq_b, qn_b, nbr, user_b,
                                        iui_s, iui_b, out);
}